// Round 2
// baseline (319.441 us; speedup 1.0000x reference)
//
#include <hip/hip_runtime.h>
#include <stdint.h>

// Problem dims (fixed): x[4,4096,2048] f32, W[2048,2048] f32, bias[2048] f32
#define NTOK   16384
#define DIN    2048
#define DOUT   2048
#define WELEMS (DOUT * DIN)
#define NPART  512

typedef int v4i  __attribute__((ext_vector_type(4)));
typedef int v16i __attribute__((ext_vector_type(16)));

// async global->LDS, 16B per lane. LDS dest must be wave-uniform base + lane*16.
__device__ __forceinline__ void load_lds16(const void* g, void* s) {
    __builtin_amdgcn_global_load_lds(
        (const __attribute__((address_space(1))) void*)(uintptr_t)g,
        (__attribute__((address_space(3))) void*)(uintptr_t)s,
        16, 0, 0);
}

// ---- kernel 1a: per-block partial sums of |W| (no atomics) ----------------
__global__ __launch_bounds__(256) void wabs_partial(const float* __restrict__ w,
                                                    double* __restrict__ part) {
    double s = 0.0;
    int idx = blockIdx.x * 256 + threadIdx.x;
    const int stride = NPART * 256;                 // float4 stride
#pragma unroll
    for (int i = 0; i < WELEMS / 4 / stride; i++) { // 8 iters
        float4 r = ((const float4*)w)[idx + i * stride];
        s += (double)(fabsf(r.x) + fabsf(r.y)) + (double)(fabsf(r.z) + fabsf(r.w));
    }
    for (int o = 32; o; o >>= 1) s += __shfl_down(s, o);
    __shared__ double sm[4];
    if ((threadIdx.x & 63) == 0) sm[threadIdx.x >> 6] = s;
    __syncthreads();
    if (threadIdx.x == 0) part[blockIdx.x] = sm[0] + sm[1] + sm[2] + sm[3];
}

// ---- kernel 1b: reduce partials -> wsum (single block) --------------------
__global__ __launch_bounds__(256) void wabs_reduce(const double* __restrict__ part,
                                                   double* __restrict__ wsum) {
    double s = part[threadIdx.x] + part[256 + threadIdx.x];
    for (int o = 32; o; o >>= 1) s += __shfl_down(s, o);
    __shared__ double sm[4];
    if ((threadIdx.x & 63) == 0) sm[threadIdx.x >> 6] = s;
    __syncthreads();
    if (threadIdx.x == 0) wsum[0] = sm[0] + sm[1] + sm[2] + sm[3];
}

// ---- kernel 2: ternarize W -> int8 {-1,0,1} -------------------------------
__global__ __launch_bounds__(256) void wtern(const float* __restrict__ w,
                                             const double* __restrict__ wsum,
                                             signed char* __restrict__ t) {
    int idx = blockIdx.x * 256 + threadIdx.x;
    float mean = (float)(wsum[0] * (1.0 / (double)WELEMS));
    float sw = 1.0f / fmaxf(mean, 1e-8f);
    float4 r = ((const float4*)w)[idx];
    float v[4] = { r.x, r.y, r.z, r.w };
    uint32_t p = 0;
#pragma unroll
    for (int j = 0; j < 4; j++) {
        int qi = (int)fminf(fmaxf(rintf(sw * v[j]), -1.0f), 1.0f);
        p |= ((uint32_t)(qi & 255)) << (8 * j);
    }
    ((uint32_t*)t)[idx] = p;
}

// ---- kernel 3: LayerNorm + per-token int8 quant, one WAVE per token -------
// 2048 cols / 64 lanes = 32 floats (8 float4) per lane, all reductions via
// __shfl_xor butterflies: no LDS, no __syncthreads, no cross-wave coupling.
// Lane l, j in 0..7 holds cols j*256 + l*4 .. +3 (coalesced 1KB/insn).
__global__ __launch_bounds__(256) void ln_quant(const float* __restrict__ x,
                                                const double* __restrict__ wsum,
                                                signed char* __restrict__ q,
                                                float* __restrict__ scale) {
    const int tok = blockIdx.x * 4 + (threadIdx.x >> 6);
    const int l   = threadIdx.x & 63;
    const float4* xr = (const float4*)(x + (size_t)tok * DIN);
    float4 v4[8];
#pragma unroll
    for (int j = 0; j < 8; j++) v4[j] = xr[j * 64 + l];

    float s = 0.0f, s2 = 0.0f;
#pragma unroll
    for (int j = 0; j < 8; j++) {
        s += v4[j].x + v4[j].y + v4[j].z + v4[j].w;
        s2 = fmaf(v4[j].x, v4[j].x, s2); s2 = fmaf(v4[j].y, v4[j].y, s2);
        s2 = fmaf(v4[j].z, v4[j].z, s2); s2 = fmaf(v4[j].w, v4[j].w, s2);
    }
    for (int o = 1; o < 64; o <<= 1) { s += __shfl_xor(s, o); s2 += __shfl_xor(s2, o); }
    float mu  = s * (1.0f / DIN);
    float var = s2 * (1.0f / DIN) - mu * mu;
    float rr  = 1.0f / sqrtf(var + 1e-8f);

    float md = 0.0f;
#pragma unroll
    for (int j = 0; j < 8; j++) {
        md = fmaxf(md, fabsf(v4[j].x - mu)); md = fmaxf(md, fabsf(v4[j].y - mu));
        md = fmaxf(md, fabsf(v4[j].z - mu)); md = fmaxf(md, fabsf(v4[j].w - mu));
    }
    for (int o = 1; o < 64; o <<= 1) md = fmaxf(md, __shfl_xor(md, o));

    float amax = fmaxf(rr * md, 1e-8f);     // max |y_norm|
    float sact = 127.0f / amax;

    uint32_t* qrow = (uint32_t*)(q + (size_t)tok * DIN);
#pragma unroll
    for (int j = 0; j < 8; j++) {
        uint32_t p = 0;
        float e[4] = { v4[j].x, v4[j].y, v4[j].z, v4[j].w };
#pragma unroll
        for (int k = 0; k < 4; k++) {
            float y = rr * (e[k] - mu);
            int qi = (int)fminf(fmaxf(rintf(sact * y), -128.0f), 127.0f);
            p |= ((uint32_t)(qi & 255)) << (8 * k);
        }
        qrow[j * 64 + l] = p;
    }
    if (l == 0) {
        float wmean = fmaxf((float)(wsum[0] * (1.0 / (double)WELEMS)), 1e-8f); // 1/s_w
        scale[tok] = (amax / 127.0f) * wmean;  // (1/s_act)*(1/s_w)
    }
}

// ---- kernel 4: int8 GEMM  C[m,n] = scale[m]*sum_k q[m,k]*t[n,k] + bias[n] -
// BM=BN=128, BK=64, 256 thr = 4 waves (2x2); wave 64x64 via 2x2 of
// mfma_i32_32x32x32_i8.
// 2-phase double-buffered pipeline (T3 minimum): per K-step, issue next
// tile's global_load_lds FIRST, then ds_read+MFMA the current buffer, then
// ONE __syncthreads (its vmcnt(0) drain lands after the compute phase has
// covered most of the load latency). Replaces the 1-phase sync/issue/
// sync-drain/compute structure that capped MfmaUtil at 30%.
// LDS rows are 64B (4 x 16B chunks). Swizzle: phys slot of logical chunk c
// in row r is c ^ t(r), t(r) = (r ^ (r>>2) ^ (r>>3)) & 3 — bijective per
// row, invariant under row+32/+64, and gives distinct bank-quads across
// both consecutive-8 and stride-8 lane groups of the b128 frag read
// (worst 2-way on full-wave stride-8 groups; 2-way is free per m136).
#define STAGE(BUF, KT)                                                        \
    _Pragma("unroll")                                                         \
    for (int i_ = 0; i_ < 2; i_++) {                                          \
        load_lds16(aSrc + (KT) + (size_t)(i_ * 64) * DIN,                     \
                   &As[BUF][tid * 16 + i_ * 4096]);                           \
        load_lds16(bSrc + (KT) + (size_t)(i_ * 64) * DIN,                     \
                   &Bs[BUF][tid * 16 + i_ * 4096]);                           \
    }

#define COMPUTE(BUF)                                                          \
    _Pragma("unroll")                                                         \
    for (int ks_ = 0; ks_ < 2; ks_++) {                                       \
        const int c_ = ((ks_ * 2 + half) ^ sw) * 16;                          \
        v4i af0 = *(const v4i*)&As[BUF][rm0 * 64 + c_];                       \
        v4i af1 = *(const v4i*)&As[BUF][(rm0 + 32) * 64 + c_];                \
        v4i bf0 = *(const v4i*)&Bs[BUF][rn0 * 64 + c_];                       \
        v4i bf1 = *(const v4i*)&Bs[BUF][(rn0 + 32) * 64 + c_];                \
        acc[0][0] = __builtin_amdgcn_mfma_i32_32x32x32_i8(af0, bf0, acc[0][0], 0, 0, 0); \
        acc[0][1] = __builtin_amdgcn_mfma_i32_32x32x32_i8(af0, bf1, acc[0][1], 0, 0, 0); \
        acc[1][0] = __builtin_amdgcn_mfma_i32_32x32x32_i8(af1, bf0, acc[1][0], 0, 0, 0); \
        acc[1][1] = __builtin_amdgcn_mfma_i32_32x32x32_i8(af1, bf1, acc[1][1], 0, 0, 0); \
    }

__global__ __launch_bounds__(256, 4) void gemm_i8(const signed char* __restrict__ A,
                                                  const signed char* __restrict__ B,
                                                  const float* __restrict__ scale,
                                                  const float* __restrict__ bias,
                                                  float* __restrict__ C) {
    __shared__ signed char As[2][128 * 64];   // 2 x 8 KB
    __shared__ signed char Bs[2][128 * 64];   // 2 x 8 KB  (32 KB total, as before)

    const int tid  = threadIdx.x;
    // T1 XCD-aware swizzle: nwg = 2048, 8 XCDs, 256 blocks/XCD chunk.
    // Within a chunk bn is fastest -> each XCD reuses one 256KB Q-panel
    // across all 16 bn before moving on; t (4MB) stays L2-resident.
    const int wg   = blockIdx.x;
    const int swg  = (wg & 7) * 256 + (wg >> 3);
    const int bn   = swg & 15, bm = swg >> 4;
    const int lane = tid & 63, wid = tid >> 6;
    const int l31  = lane & 31, half = lane >> 5;
    const int waveM = (wid & 1) * 64, waveN = (wid >> 1) * 64;

    // staging: each insn moves 64 rows x 64B (256 lanes x 16B).
    const int srow   = tid >> 2;                                   // 0..63
    const int schunk = (tid & 3) ^ ((srow ^ (srow >> 2) ^ (srow >> 3)) & 3);
    const signed char* aSrc = A + (size_t)(bm * 128 + srow) * DIN + schunk * 16;
    const signed char* bSrc = B + (size_t)(bn * 128 + srow) * DIN + schunk * 16;

    v16i acc[2][2] = {};

    const int rm0 = waveM + l31;        // A rows for mi=0 (mi=1: +32)
    const int rn0 = waveN + l31;        // B rows for ni=0
    const int sw  = (l31 ^ (l31 >> 2) ^ (l31 >> 3)) & 3;  // row swizzle bits
                                        // (invariant under +32/+64 row offsets)

    STAGE(0, 0);
    __syncthreads();                    // buf0 ready
    for (int kt = 0; kt < DIN; kt += 128) {
        STAGE(1, kt + 64);              // prefetch next half-step into buf1
        COMPUTE(0);                     // overlaps the loads above
        __syncthreads();                // drain vmcnt -> buf1 ready, buf0 free
        if (kt + 128 < DIN) STAGE(0, kt + 128);
        COMPUTE(1);
        __syncthreads();
    }

    // epilogue: 32x32 C/D layout col=lane&31, row=(reg&3)+8*(reg>>2)+4*(lane>>5)
    const int mBase = bm * 128 + waveM;
    const int nBase = bn * 128 + waveN;
#pragma unroll
    for (int ni = 0; ni < 2; ni++) {
        int n = nBase + ni * 32 + l31;
        float bz = bias[n];
#pragma unroll
        for (int mi = 0; mi < 2; mi++) {
#pragma unroll
            for (int reg = 0; reg < 16; reg++) {
                int row = (reg & 3) + 8 * (reg >> 2) + 4 * half;
                int m = mBase + mi * 32 + row;
                C[(size_t)m * DOUT + n] = fmaf(scale[m], (float)acc[mi][ni][reg], bz);
            }
        }
    }
}

extern "C" void kernel_launch(void* const* d_in, const int* in_sizes, int n_in,
                              void* d_out, int out_size, void* d_ws, size_t ws_size,
                              hipStream_t stream) {
    const float* x    = (const float*)d_in[0];   // f32 [16384, 2048]
    const float* w    = (const float*)d_in[1];   // f32 [2048, 2048]
    const float* bias = (const float*)d_in[2];   // f32 [2048]
    float* out = (float*)d_out;                  // f32 [16384, 2048]

    char* ws = (char*)d_ws;
    signed char* q     = (signed char*)ws;                               // 32 MB
    signed char* t     = (signed char*)(ws + (size_t)NTOK * DIN);        // 4 MB
    float*       scale = (float*)(ws + (size_t)NTOK * DIN + WELEMS);     // 64 KB
    char*        tail  = ws + (size_t)NTOK * DIN + WELEMS + NTOK * 4;
    double*      wsum  = (double*)tail;                                  // 8 B
    double*      part  = (double*)(tail + 4096);                         // 4 KB

    wabs_partial<<<NPART, 256, 0, stream>>>(w, part);
    wabs_reduce<<<1, 256, 0, stream>>>(part, wsum);
    wtern<<<WELEMS / (256 * 4), 256, 0, stream>>>(w, wsum, t);
    ln_quant<<<NTOK / 4, 256, 0, stream>>>(x, wsum, q, scale);
    gemm_i8<<<(NTOK / 128) * (DOUT / 128), 256, 0, stream>>>(q, t, scale, bias, out);
}

// Round 5
// 315.536 us; speedup vs baseline: 1.0124x; 1.0124x over previous
//
#include <hip/hip_runtime.h>
#include <stdint.h>

// Problem dims (fixed): x[4,4096,2048] f32, W[2048,2048] f32, bias[2048] f32
#define NTOK   16384
#define DIN    2048
#define DOUT   2048
#define WELEMS (DOUT * DIN)
#define NPART  512

typedef int v4i  __attribute__((ext_vector_type(4)));
typedef int v16i __attribute__((ext_vector_type(16)));

// async global->LDS, 16B per lane. LDS dest must be wave-uniform base + lane*16.
__device__ __forceinline__ void load_lds16(const void* g, void* s) {
    __builtin_amdgcn_global_load_lds(
        (const __attribute__((address_space(1))) void*)(uintptr_t)g,
        (__attribute__((address_space(3))) void*)(uintptr_t)s,
        16, 0, 0);
}

// ---- kernel 1a: per-block partial sums of |W| (no atomics) ----------------
__global__ __launch_bounds__(256) void wabs_partial(const float* __restrict__ w,
                                                    double* __restrict__ part) {
    double s = 0.0;
    int idx = blockIdx.x * 256 + threadIdx.x;
    const int stride = NPART * 256;                 // float4 stride
#pragma unroll
    for (int i = 0; i < WELEMS / 4 / stride; i++) { // 8 iters
        float4 r = ((const float4*)w)[idx + i * stride];
        s += (double)(fabsf(r.x) + fabsf(r.y)) + (double)(fabsf(r.z) + fabsf(r.w));
    }
    for (int o = 32; o; o >>= 1) s += __shfl_down(s, o);
    __shared__ double sm[4];
    if ((threadIdx.x & 63) == 0) sm[threadIdx.x >> 6] = s;
    __syncthreads();
    if (threadIdx.x == 0) part[blockIdx.x] = sm[0] + sm[1] + sm[2] + sm[3];
}

// ---- kernel 1b: reduce partials -> wsum (single block) --------------------
__global__ __launch_bounds__(256) void wabs_reduce(const double* __restrict__ part,
                                                   double* __restrict__ wsum) {
    double s = part[threadIdx.x] + part[256 + threadIdx.x];
    for (int o = 32; o; o >>= 1) s += __shfl_down(s, o);
    __shared__ double sm[4];
    if ((threadIdx.x & 63) == 0) sm[threadIdx.x >> 6] = s;
    __syncthreads();
    if (threadIdx.x == 0) wsum[0] = sm[0] + sm[1] + sm[2] + sm[3];
}

// ---- kernel 2: ternarize W -> int8 {-1,0,1} -------------------------------
__global__ __launch_bounds__(256) void wtern(const float* __restrict__ w,
                                             const double* __restrict__ wsum,
                                             signed char* __restrict__ t) {
    int idx = blockIdx.x * 256 + threadIdx.x;
    float mean = (float)(wsum[0] * (1.0 / (double)WELEMS));
    float sw = 1.0f / fmaxf(mean, 1e-8f);
    float4 r = ((const float4*)w)[idx];
    float v[4] = { r.x, r.y, r.z, r.w };
    uint32_t p = 0;
#pragma unroll
    for (int j = 0; j < 4; j++) {
        int qi = (int)fminf(fmaxf(rintf(sw * v[j]), -1.0f), 1.0f);
        p |= ((uint32_t)(qi & 255)) << (8 * j);
    }
    ((uint32_t*)t)[idx] = p;
}

// ---- kernel 3: LayerNorm + per-token int8 quant, one WAVE per token -------
__global__ __launch_bounds__(256) void ln_quant(const float* __restrict__ x,
                                                const double* __restrict__ wsum,
                                                signed char* __restrict__ q,
                                                float* __restrict__ scale) {
    const int tok = blockIdx.x * 4 + (threadIdx.x >> 6);
    const int l   = threadIdx.x & 63;
    const float4* xr = (const float4*)(x + (size_t)tok * DIN);
    float4 v4[8];
#pragma unroll
    for (int j = 0; j < 8; j++) v4[j] = xr[j * 64 + l];

    float s = 0.0f, s2 = 0.0f;
#pragma unroll
    for (int j = 0; j < 8; j++) {
        s += v4[j].x + v4[j].y + v4[j].z + v4[j].w;
        s2 = fmaf(v4[j].x, v4[j].x, s2); s2 = fmaf(v4[j].y, v4[j].y, s2);
        s2 = fmaf(v4[j].z, v4[j].z, s2); s2 = fmaf(v4[j].w, v4[j].w, s2);
    }
    for (int o = 1; o < 64; o <<= 1) { s += __shfl_xor(s, o); s2 += __shfl_xor(s2, o); }
    float mu  = s * (1.0f / DIN);
    float var = s2 * (1.0f / DIN) - mu * mu;
    float rr  = 1.0f / sqrtf(var + 1e-8f);

    float md = 0.0f;
#pragma unroll
    for (int j = 0; j < 8; j++) {
        md = fmaxf(md, fabsf(v4[j].x - mu)); md = fmaxf(md, fabsf(v4[j].y - mu));
        md = fmaxf(md, fabsf(v4[j].z - mu)); md = fmaxf(md, fabsf(v4[j].w - mu));
    }
    for (int o = 1; o < 64; o <<= 1) md = fmaxf(md, __shfl_xor(md, o));

    float amax = fmaxf(rr * md, 1e-8f);     // max |y_norm|
    float sact = 127.0f / amax;

    uint32_t* qrow = (uint32_t*)(q + (size_t)tok * DIN);
#pragma unroll
    for (int j = 0; j < 8; j++) {
        uint32_t p = 0;
        float e[4] = { v4[j].x, v4[j].y, v4[j].z, v4[j].w };
#pragma unroll
        for (int k = 0; k < 4; k++) {
            float y = rr * (e[k] - mu);
            int qi = (int)fminf(fmaxf(rintf(sact * y), -128.0f), 127.0f);
            p |= ((uint32_t)(qi & 255)) << (8 * k);
        }
        qrow[j * 64 + l] = p;
    }
    if (l == 0) {
        float wmean = fmaxf((float)(wsum[0] * (1.0 / (double)WELEMS)), 1e-8f); // 1/s_w
        scale[tok] = (amax / 127.0f) * wmean;  // (1/s_act)*(1/s_w)
    }
}

// ---- kernel 4: int8 GEMM, 256x256 tile, 8-phase counted-vmcnt schedule ----
// C[m,n] = scale[m] * sum_k q[m,k] * t[n,k] + bias[n]
// BM=BN=256, BK=64, 512 thr = 8 waves (2M x 4N), per-wave 128x64 output via
// 4x2 of mfma_i32_32x32x32_i8. LDS: ring of 4 K-tile slots (A 16KB + B 16KB
// each) = 128 KB -> 1 block/CU (matches verified 256^2 8-phase template).
// Schedule (T3+T4+T5): iteration i covers K-tiles 2i,2i+1 in 8 phases; each
// phase = {2-4 ds_read_b128, 1 global_load_lds (stages tiles 2i+2/2i+3, i.e.
// 4-8 phases ahead), sched_barrier+s_barrier, setprio(1), 4 MFMA, setprio(0),
// [vmcnt(4) at phases 4/8 only], sched_barrier+s_barrier}. Counted vmcnt:
// loads retire in order; allowing the newest 4 outstanding guarantees the
// tile read 1 phase later has fully landed, while keeping prefetch in flight
// across barriers (never vmcnt(0) in the main loop). Tail iteration peeled:
// no staging, vmcnt(0) at phase 4.
// LDS swizzle (T2): 64B rows, phys 16B-chunk = logical ^ t(r),
// t(r) = (r ^ (r>>2) ^ (r>>3)) & 3 — depends only on row bits 0..4, so it is
// invariant under the +32/+64/+128 row offsets of frag reads (measured 0
// bank conflicts with this family in the 128^2 kernel).
#define G_BM 256
#define G_BK 64
#define G_NITER (DIN / (G_BK * 2))   // 16

#define VMCNT4 asm volatile("s_waitcnt vmcnt(4)" ::: "memory")
#define VMCNT0 asm volatile("s_waitcnt vmcnt(0)" ::: "memory")
#define NOSTMT ((void)0)
#define BARRIER_ do { __builtin_amdgcn_sched_barrier(0); \
                      __builtin_amdgcn_s_barrier();      \
                      __builtin_amdgcn_sched_barrier(0); } while (0)

// stage one 128-row half (8KB) of tile-slot S's A or B at K-offset KT
#define STAGE_A(S, KT, RB) load_lds16(aSrc + (KT) + (size_t)((RB) * 128) * DIN, \
                                      &As[S][(RB) * 8192 + tid * 16])
#define STAGE_B(S, KT, RB) load_lds16(bSrc + (KT) + (size_t)((RB) * 128) * DIN, \
                                      &Bs[S][(RB) * 8192 + tid * 16])

#define PHASE(S, KS, MH, STAGE_STMT, WAIT_STMT) do {                          \
    const int c_ = (((KS) * 2 + half) ^ sw) * 16;                             \
    v4i a0_ = *(const v4i*)&As[S][(arow + (MH) * 64) * 64 + c_];              \
    v4i a1_ = *(const v4i*)&As[S][(arow + (MH) * 64 + 32) * 64 + c_];         \
    if ((MH) == 0) {                                                          \
        bf0 = *(const v4i*)&Bs[S][brow * 64 + c_];                            \
        bf1 = *(const v4i*)&Bs[S][(brow + 32) * 64 + c_];                     \
    }                                                                         \
    STAGE_STMT;                                                               \
    BARRIER_;                                                                 \
    __builtin_amdgcn_s_setprio(1);                                            \
    acc[(MH)*2  ][0] = __builtin_amdgcn_mfma_i32_32x32x32_i8(a0_, bf0, acc[(MH)*2  ][0], 0, 0, 0); \
    acc[(MH)*2  ][1] = __builtin_amdgcn_mfma_i32_32x32x32_i8(a0_, bf1, acc[(MH)*2  ][1], 0, 0, 0); \
    acc[(MH)*2+1][0] = __builtin_amdgcn_mfma_i32_32x32x32_i8(a1_, bf0, acc[(MH)*2+1][0], 0, 0, 0); \
    acc[(MH)*2+1][1] = __builtin_amdgcn_mfma_i32_32x32x32_i8(a1_, bf1, acc[(MH)*2+1][1], 0, 0, 0); \
    __builtin_amdgcn_s_setprio(0);                                            \
    WAIT_STMT;                                                                \
    BARRIER_;                                                                 \
} while (0)

__global__ __launch_bounds__(512, 2) void gemm_i8(const signed char* __restrict__ A,
                                                  const signed char* __restrict__ B,
                                                  const float* __restrict__ scale,
                                                  const float* __restrict__ bias,
                                                  float* __restrict__ C) {
    __shared__ signed char As[4][G_BM * G_BK];   // 64 KB
    __shared__ signed char Bs[4][G_BM * G_BK];   // 64 KB

    const int tid = threadIdx.x;
    // XCD swizzle: nwg = 512 = 8 XCDs x 64; within a chunk bn (8) fastest so
    // each XCD reuses one 2MB Q-panel across all bn; t (4MB) L2-resident.
    const int wg  = blockIdx.x;
    const int swg = (wg & 7) * 64 + (wg >> 3);
    const int bn  = swg & 7, bm = swg >> 3;          // bn 0..7, bm 0..63
    const int lane = tid & 63, wid = tid >> 6;       // 8 waves
    const int l31 = lane & 31, half = lane >> 5;
    const int waveM = (wid >> 2) * 128, waveN = (wid & 3) * 64;

    // staging: each insn moves 128 rows x 64B (512 lanes x 16B), linear LDS
    // dest tid*16; global source pre-swizzled by the chunk XOR.
    const int srow   = tid >> 2;                                   // 0..127
    const int schunk = (tid & 3) ^ ((srow ^ (srow >> 2) ^ (srow >> 3)) & 3);
    const signed char* aSrc = A + (size_t)(bm * 256 + srow) * DIN + schunk * 16;
    const signed char* bSrc = B + (size_t)(bn * 256 + srow) * DIN + schunk * 16;

    const int sw   = (l31 ^ (l31 >> 2) ^ (l31 >> 3)) & 3;  // read-side XOR
    const int arow = waveM + l31;       // + MH*64 (+32 for second frag)
    const int brow = waveN + l31;       // + 32 for second frag

    v16i acc[4][2] = {};
    v4i bf0, bf1;

    // prologue: stage tiles 0 and 1 (8 loads/thread), wait tile 0 landed.
    STAGE_A(0, 0, 0); STAGE_A(0, 0, 1); STAGE_B(0, 0, 0); STAGE_B(0, 0, 1);
    STAGE_A(1, G_BK, 0); STAGE_A(1, G_BK, 1); STAGE_B(1, G_BK, 0); STAGE_B(1, G_BK, 1);
    VMCNT4;
    BARRIER_;

    for (int i = 0; i < G_NITER - 1; ++i) {           // i = 0..14
        const int ta = 2 * i, tb = 2 * i + 1;
        const int sa = ta & 3, sb = tb & 3;
        const int s2 = (ta + 2) & 3, s3 = (tb + 2) & 3;
        const int k2 = (ta + 2) * G_BK, k3 = (tb + 2) * G_BK;
        PHASE(sa, 0, 0, STAGE_A(s2, k2, 0), NOSTMT);
        PHASE(sa, 0, 1, STAGE_A(s2, k2, 1), NOSTMT);
        PHASE(sa, 1, 0, STAGE_B(s2, k2, 0), NOSTMT);
        PHASE(sa, 1, 1, STAGE_B(s2, k2, 1), VMCNT4);   // tile tb landed
        PHASE(sb, 0, 0, STAGE_A(s3, k3, 0), NOSTMT);
        PHASE(sb, 0, 1, STAGE_A(s3, k3, 1), NOSTMT);
        PHASE(sb, 1, 0, STAGE_B(s3, k3, 0), NOSTMT);
        PHASE(sb, 1, 1, STAGE_B(s3, k3, 1), VMCNT4);   // tile ta+2 landed
    }
    // tail iteration: tiles 30 (slot 2) and 31 (slot 3), no staging.
    PHASE(2, 0, 0, NOSTMT, NOSTMT);
    PHASE(2, 0, 1, NOSTMT, NOSTMT);
    PHASE(2, 1, 0, NOSTMT, NOSTMT);
    PHASE(2, 1, 1, NOSTMT, VMCNT0);                    // tile 31 landed
    PHASE(3, 0, 0, NOSTMT, NOSTMT);
    PHASE(3, 0, 1, NOSTMT, NOSTMT);
    PHASE(3, 1, 0, NOSTMT, NOSTMT);
    PHASE(3, 1, 1, NOSTMT, NOSTMT);

    // epilogue: 32x32 C/D layout col=lane&31, row=(reg&3)+8*(reg>>2)+4*(lane>>5)
    const int mBase = bm * 256 + waveM;
    const int nBase = bn * 256 + waveN;
#pragma unroll
    for (int ni = 0; ni < 2; ni++) {
        int n = nBase + ni * 32 + l31;
        float bz = bias[n];
#pragma unroll
        for (int mi = 0; mi < 4; mi++) {
#pragma unroll
            for (int reg = 0; reg < 16; reg++) {
                int row = (reg & 3) + 8 * (reg >> 2) + 4 * half;
                int m = mBase + mi * 32 + row;
                C[(size_t)m * DOUT + n] = fmaf(scale[m], (float)acc[mi][ni][reg], bz);
            }
        }
    }
}

extern "C" void kernel_launch(void* const* d_in, const int* in_sizes, int n_in,
                              void* d_out, int out_size, void* d_ws, size_t ws_size,
                              hipStream_t stream) {
    const float* x    = (const float*)d_in[0];   // f32 [16384, 2048]
    const float* w    = (const float*)d_in[1];   // f32 [2048, 2048]
    const float* bias = (const float*)d_in[2];   // f32 [2048]
    float* out = (float*)d_out;                  // f32 [16384, 2048]

    char* ws = (char*)d_ws;
    signed char* q     = (signed char*)ws;                               // 32 MB
    signed char* t     = (signed char*)(ws + (size_t)NTOK * DIN);        // 4 MB
    float*       scale = (float*)(ws + (size_t)NTOK * DIN + WELEMS);     // 64 KB
    char*        tail  = ws + (size_t)NTOK * DIN + WELEMS + NTOK * 4;
    double*      wsum  = (double*)tail;                                  // 8 B
    double*      part  = (double*)(tail + 4096);                         // 4 KB

    wabs_partial<<<NPART, 256, 0, stream>>>(w, part);
    wabs_reduce<<<1, 256, 0, stream>>>(part, wsum);
    wtern<<<WELEMS / (256 * 4), 256, 0, stream>>>(w, wsum, t);
    ln_quant<<<NTOK / 4, 256, 0, stream>>>(x, wsum, q, scale);
    gemm_i8<<<(NTOK / 256) * (DOUT / 256), 512, 0, stream>>>(q, t, scale, bias, out);
}

// Round 8
// 314.687 us; speedup vs baseline: 1.0151x; 1.0027x over previous
//
#include <hip/hip_runtime.h>
#include <stdint.h>

// Problem dims (fixed): x[4,4096,2048] f32, W[2048,2048] f32, bias[2048] f32
#define NTOK   16384
#define DIN    2048
#define DOUT   2048
#define WELEMS (DOUT * DIN)
#define NPART  512

typedef int v4i  __attribute__((ext_vector_type(4)));
typedef int v16i __attribute__((ext_vector_type(16)));

// async global->LDS, 16B per lane. LDS dest must be wave-uniform base + lane*16.
__device__ __forceinline__ void load_lds16(const void* g, void* s) {
    __builtin_amdgcn_global_load_lds(
        (const __attribute__((address_space(1))) void*)(uintptr_t)g,
        (__attribute__((address_space(3))) void*)(uintptr_t)s,
        16, 0, 0);
}

// ---- kernel 1: per-block partial sums of |W| (no atomics) -----------------
__global__ __launch_bounds__(256) void wabs_partial(const float* __restrict__ w,
                                                    double* __restrict__ part) {
    double s = 0.0;
    int idx = blockIdx.x * 256 + threadIdx.x;
    const int stride = NPART * 256;                 // float4 stride
#pragma unroll
    for (int i = 0; i < WELEMS / 4 / stride; i++) { // 8 iters
        float4 r = ((const float4*)w)[idx + i * stride];
        s += (double)(fabsf(r.x) + fabsf(r.y)) + (double)(fabsf(r.z) + fabsf(r.w));
    }
    for (int o = 32; o; o >>= 1) s += __shfl_down(s, o);
    __shared__ double sm[4];
    if ((threadIdx.x & 63) == 0) sm[threadIdx.x >> 6] = s;
    __syncthreads();
    if (threadIdx.x == 0) part[blockIdx.x] = sm[0] + sm[1] + sm[2] + sm[3];
}

// ---- kernel 2: ternarize W -> int8 {-1,0,1} (fused final reduce) ----------
// Each block redundantly reduces part[512] (4 KB L2-resident read, ~free)
// -> removes the single-block wabs_reduce launch from the serial chain.
// Block 0 also publishes wsum[0] for ln_quant (stream-ordered after us).
__global__ __launch_bounds__(256) void wtern(const float* __restrict__ w,
                                             const double* __restrict__ part,
                                             double* __restrict__ wsum,
                                             signed char* __restrict__ t) {
    double s = part[threadIdx.x] + part[256 + threadIdx.x];
    for (int o = 32; o; o >>= 1) s += __shfl_down(s, o);
    __shared__ double sm[4];
    if ((threadIdx.x & 63) == 0) sm[threadIdx.x >> 6] = s;
    __syncthreads();
    double tot = sm[0] + sm[1] + sm[2] + sm[3];
    if (blockIdx.x == 0 && threadIdx.x == 0) wsum[0] = tot;

    int idx = blockIdx.x * 256 + threadIdx.x;
    float mean = (float)(tot * (1.0 / (double)WELEMS));
    float sw = 1.0f / fmaxf(mean, 1e-8f);
    float4 r = ((const float4*)w)[idx];
    float v[4] = { r.x, r.y, r.z, r.w };
    uint32_t p = 0;
#pragma unroll
    for (int j = 0; j < 4; j++) {
        int qi = (int)fminf(fmaxf(rintf(sw * v[j]), -1.0f), 1.0f);
        p |= ((uint32_t)(qi & 255)) << (8 * j);
    }
    ((uint32_t*)t)[idx] = p;
}

// ---- kernel 3: LayerNorm + per-token int8 quant, one WAVE per token -------
__global__ __launch_bounds__(256) void ln_quant(const float* __restrict__ x,
                                                const double* __restrict__ wsum,
                                                signed char* __restrict__ q,
                                                float* __restrict__ scale) {
    const int tok = blockIdx.x * 4 + (threadIdx.x >> 6);
    const int l   = threadIdx.x & 63;
    const float4* xr = (const float4*)(x + (size_t)tok * DIN);
    float4 v4[8];
#pragma unroll
    for (int j = 0; j < 8; j++) v4[j] = xr[j * 64 + l];

    float s = 0.0f, s2 = 0.0f;
#pragma unroll
    for (int j = 0; j < 8; j++) {
        s += v4[j].x + v4[j].y + v4[j].z + v4[j].w;
        s2 = fmaf(v4[j].x, v4[j].x, s2); s2 = fmaf(v4[j].y, v4[j].y, s2);
        s2 = fmaf(v4[j].z, v4[j].z, s2); s2 = fmaf(v4[j].w, v4[j].w, s2);
    }
    for (int o = 1; o < 64; o <<= 1) { s += __shfl_xor(s, o); s2 += __shfl_xor(s2, o); }
    float mu  = s * (1.0f / DIN);
    float var = s2 * (1.0f / DIN) - mu * mu;
    float rr  = 1.0f / sqrtf(var + 1e-8f);

    float md = 0.0f;
#pragma unroll
    for (int j = 0; j < 8; j++) {
        md = fmaxf(md, fabsf(v4[j].x - mu)); md = fmaxf(md, fabsf(v4[j].y - mu));
        md = fmaxf(md, fabsf(v4[j].z - mu)); md = fmaxf(md, fabsf(v4[j].w - mu));
    }
    for (int o = 1; o < 64; o <<= 1) md = fmaxf(md, __shfl_xor(md, o));

    float amax = fmaxf(rr * md, 1e-8f);     // max |y_norm|
    float sact = 127.0f / amax;

    uint32_t* qrow = (uint32_t*)(q + (size_t)tok * DIN);
#pragma unroll
    for (int j = 0; j < 8; j++) {
        uint32_t p = 0;
        float e[4] = { v4[j].x, v4[j].y, v4[j].z, v4[j].w };
#pragma unroll
        for (int k = 0; k < 4; k++) {
            float y = rr * (e[k] - mu);
            int qi = (int)fminf(fmaxf(rintf(sact * y), -128.0f), 127.0f);
            p |= ((uint32_t)(qi & 255)) << (8 * k);
        }
        qrow[j * 64 + l] = p;
    }
    if (l == 0) {
        float wmean = fmaxf((float)(wsum[0] * (1.0 / (double)WELEMS)), 1e-8f); // 1/s_w
        scale[tok] = (amax / 127.0f) * wmean;  // (1/s_act)*(1/s_w)
    }
}

// ---- kernel 4: int8 GEMM, 256x256, 8-phase SINGLE-barrier pipeline --------
// C[m,n] = scale[m] * sum_k q[m,k] * t[n,k] + bias[n]
// Geometry unchanged from R5 (BM=BN=256, BK=64, 8 waves 2Mx4N, wave 128x64,
// ring of 4 K-tile slots = 128 KB LDS, chunk-XOR swizzle, XCD grid swizzle).
// R5 measured: MfmaUtil 34%, 0 conflicts — 2-barrier phases serialized the
// read-region (~288 cyc) and MFMA-region (~293 cyc). Fix: one-phase-ahead
// REGISTER frag prefetch + ONE barrier per phase: phase p = { ds_read frags
// for p+1, stage, MFMA on regs read at p-1, [counted vmcnt], barrier }.
// vmcnt induction (per wave): entry t=4 (tile 2i+1 outstanding); p0..p2
// stage -> 7, VMCNT3@p2 retires tile 2i+1's 4 -> barrier -> p3 reads slot
// sb safe BLOCK-WIDE; p3..p6 stage -> 7, VMCNT3@p6 retires tile 2i+2 ->
// barrier -> p7 reads slot s2 safe; p7 stages -> 4 = invariant. Tail peeled
// with vmcnt(0). WAR: a slot's last ds_read completes before its consuming
// MFMA (compiler lgkmcnt) which precedes that phase's barrier; the
// overwriting stage issues >= 4 barriers later. Safe.
// R7 BUGFIX: prologue previously read p0 frags after vmcnt(4) but BEFORE
// the barrier — vmcnt is per-wave, so rows staged by OTHER waves (e.g.
// wave 0 reads rows 16..31, staged by wave 1) were not guaranteed landed:
// cross-wave race, absmax 1686. Correct order: stage -> vmcnt(4) ->
// BARRIER -> read p0 frags (reads of other waves' data must follow a
// barrier that follows every wave's own vmcnt).
#define G_BM 256
#define G_BK 64
#define G_NITER (DIN / (G_BK * 2))   // 16

#define VMCNT3 asm volatile("s_waitcnt vmcnt(3)" ::: "memory")
#define VMCNT0 asm volatile("s_waitcnt vmcnt(0)" ::: "memory")
#define NOSTMT ((void)0)

// stage one 128-row half (8KB) of tile-slot S's A or B at K-offset KT
#define STAGE_A(S, KT, RB) load_lds16(aSrc + (KT) + (size_t)((RB) * 128) * DIN, \
                                      &As[S][(RB) * 8192 + tid * 16])
#define STAGE_B(S, KT, RB) load_lds16(bSrc + (KT) + (size_t)((RB) * 128) * DIN, \
                                      &Bs[S][(RB) * 8192 + tid * 16])

// NS/NKS/NMH: frags to prefetch (for phase p+1). MH: current phase's output
// quadrant. DOREAD=0 only on the very last phase.
#define PH(NS, NKS, NMH, MH, DOREAD, STAGE_STMT, WAIT_STMT) do {              \
    if (DOREAD) {                                                             \
        const int c_ = (((NKS) * 2 + half) ^ sw) * 16;                        \
        na0 = *(const v4i*)&As[NS][(arow + (NMH) * 64) * 64 + c_];            \
        na1 = *(const v4i*)&As[NS][(arow + (NMH) * 64 + 32) * 64 + c_];       \
        if ((NMH) == 0) {                                                     \
            nb0 = *(const v4i*)&Bs[NS][brow * 64 + c_];                       \
            nb1 = *(const v4i*)&Bs[NS][(brow + 32) * 64 + c_];                \
        }                                                                     \
    }                                                                         \
    STAGE_STMT;                                                               \
    __builtin_amdgcn_s_setprio(1);                                            \
    acc[(MH)*2  ][0] = __builtin_amdgcn_mfma_i32_32x32x32_i8(a0, b0, acc[(MH)*2  ][0], 0, 0, 0); \
    acc[(MH)*2  ][1] = __builtin_amdgcn_mfma_i32_32x32x32_i8(a0, b1, acc[(MH)*2  ][1], 0, 0, 0); \
    acc[(MH)*2+1][0] = __builtin_amdgcn_mfma_i32_32x32x32_i8(a1, b0, acc[(MH)*2+1][0], 0, 0, 0); \
    acc[(MH)*2+1][1] = __builtin_amdgcn_mfma_i32_32x32x32_i8(a1, b1, acc[(MH)*2+1][1], 0, 0, 0); \
    __builtin_amdgcn_s_setprio(0);                                            \
    WAIT_STMT;                                                                \
    __builtin_amdgcn_sched_barrier(0);                                        \
    __builtin_amdgcn_s_barrier();                                             \
    __builtin_amdgcn_sched_barrier(0);                                        \
    if (DOREAD) {                                                             \
        a0 = na0; a1 = na1;                                                   \
        if ((NMH) == 0) { b0 = nb0; b1 = nb1; }                               \
    }                                                                         \
} while (0)

__global__ __launch_bounds__(512, 2) void gemm_i8(const signed char* __restrict__ A,
                                                  const signed char* __restrict__ B,
                                                  const float* __restrict__ scale,
                                                  const float* __restrict__ bias,
                                                  float* __restrict__ C) {
    __shared__ signed char As[4][G_BM * G_BK];   // 64 KB
    __shared__ signed char Bs[4][G_BM * G_BK];   // 64 KB

    const int tid = threadIdx.x;
    // XCD swizzle: nwg = 512 = 8 XCDs x 64; bn fastest within a chunk.
    const int wg  = blockIdx.x;
    const int swg = (wg & 7) * 64 + (wg >> 3);
    const int bn  = swg & 7, bm = swg >> 3;          // bn 0..7, bm 0..63
    const int lane = tid & 63, wid = tid >> 6;       // 8 waves
    const int l31 = lane & 31, half = lane >> 5;
    const int waveM = (wid >> 2) * 128, waveN = (wid & 3) * 64;

    // staging: each insn moves 128 rows x 64B (512 lanes x 16B), linear LDS
    // dest tid*16; global source pre-swizzled by the chunk XOR.
    const int srow   = tid >> 2;                                   // 0..127
    const int schunk = (tid & 3) ^ ((srow ^ (srow >> 2) ^ (srow >> 3)) & 3);
    const signed char* aSrc = A + (size_t)(bm * 256 + srow) * DIN + schunk * 16;
    const signed char* bSrc = B + (size_t)(bn * 256 + srow) * DIN + schunk * 16;

    const int sw   = (l31 ^ (l31 >> 2) ^ (l31 >> 3)) & 3;  // read-side XOR
    const int arow = waveM + l31;       // + MH*64 (+32 for second frag)
    const int brow = waveN + l31;       // + 32 for second frag

    v16i acc[4][2] = {};
    v4i a0, a1, b0, b1, na0, na1, nb0, nb1;

    // prologue: stage tiles 0,1 (8 loads/thread); own-vmcnt; BARRIER (makes
    // tile 0 visible block-wide); THEN read p0 frags. (R7 fix: reads must
    // follow the barrier — vmcnt alone doesn't cover other waves' rows.)
    STAGE_A(0, 0, 0); STAGE_A(0, 0, 1); STAGE_B(0, 0, 0); STAGE_B(0, 0, 1);
    STAGE_A(1, G_BK, 0); STAGE_A(1, G_BK, 1); STAGE_B(1, G_BK, 0); STAGE_B(1, G_BK, 1);
    asm volatile("s_waitcnt vmcnt(4)" ::: "memory");
    __builtin_amdgcn_sched_barrier(0);
    __builtin_amdgcn_s_barrier();
    __builtin_amdgcn_sched_barrier(0);
    {
        const int c_ = (half ^ sw) * 16;             // ks=0
        a0 = *(const v4i*)&As[0][arow * 64 + c_];
        a1 = *(const v4i*)&As[0][(arow + 32) * 64 + c_];
        b0 = *(const v4i*)&Bs[0][brow * 64 + c_];
        b1 = *(const v4i*)&Bs[0][(brow + 32) * 64 + c_];
    }
    nb0 = b0; nb1 = b1;

    for (int i = 0; i < G_NITER - 1; ++i) {           // i = 0..14
        const int ta = 2 * i;
        const int sa = ta & 3, sb = (ta + 1) & 3;
        const int s2 = (ta + 2) & 3, s3 = (ta + 3) & 3;
        const int k2 = (ta + 2) * G_BK, k3 = (ta + 3) * G_BK;
        PH(sa, 0, 1, 0, 1, STAGE_A(s2, k2, 0), NOSTMT);  // compute (sa,0,0)
        PH(sa, 1, 0, 1, 1, STAGE_A(s2, k2, 1), NOSTMT);  // compute (sa,0,1)
        PH(sa, 1, 1, 0, 1, STAGE_B(s2, k2, 0), VMCNT3);  // tile ta+1 landed
        PH(sb, 0, 0, 1, 1, STAGE_B(s2, k2, 1), NOSTMT);  // reads sb: safe
        PH(sb, 0, 1, 0, 1, STAGE_A(s3, k3, 0), NOSTMT);
        PH(sb, 1, 0, 1, 1, STAGE_A(s3, k3, 1), NOSTMT);
        PH(sb, 1, 1, 0, 1, STAGE_B(s3, k3, 0), VMCNT3);  // tile ta+2 landed
        PH(s2, 0, 0, 1, 1, STAGE_B(s3, k3, 1), NOSTMT);  // reads s2: safe
    }
    // tail: tiles 30 (slot 2), 31 (slot 3); no staging.
    PH(2, 0, 1, 0, 1, NOSTMT, NOSTMT);
    PH(2, 1, 0, 1, 1, NOSTMT, NOSTMT);
    PH(2, 1, 1, 0, 1, NOSTMT, VMCNT0);                   // tile 31 landed
    PH(3, 0, 0, 1, 1, NOSTMT, NOSTMT);
    PH(3, 0, 1, 0, 1, NOSTMT, NOSTMT);
    PH(3, 1, 0, 1, 1, NOSTMT, NOSTMT);
    PH(3, 1, 1, 0, 1, NOSTMT, NOSTMT);
    PH(0, 0, 0, 1, 0, NOSTMT, NOSTMT);                   // last: no read

    // epilogue: 32x32 C/D layout col=lane&31, row=(reg&3)+8*(reg>>2)+4*(lane>>5)
    const int mBase = bm * 256 + waveM;
    const int nBase = bn * 256 + waveN;
#pragma unroll
    for (int ni = 0; ni < 2; ni++) {
        int n = nBase + ni * 32 + l31;
        float bz = bias[n];
#pragma unroll
        for (int mi = 0; mi < 4; mi++) {
#pragma unroll
            for (int reg = 0; reg < 16; reg++) {
                int row = (reg & 3) + 8 * (reg >> 2) + 4 * half;
                int m = mBase + mi * 32 + row;
                C[(size_t)m * DOUT + n] = fmaf(scale[m], (float)acc[mi][ni][reg], bz);
            }
        }
    }
}

extern "C" void kernel_launch(void* const* d_in, const int* in_sizes, int n_in,
                              void* d_out, int out_size, void* d_ws, size_t ws_size,
                              hipStream_t stream) {
    const float* x    = (const float*)d_in[0];   // f32 [16384, 2048]
    const float* w    = (const float*)d_in[1];   // f32 [2048, 2048]
    const float* bias = (const float*)d_in[2];   // f32 [2048]
    float* out = (float*)d_out;                  // f32 [16384, 2048]

    char* ws = (char*)d_ws;
    signed char* q     = (signed char*)ws;                               // 32 MB
    signed char* t     = (signed char*)(ws + (size_t)NTOK * DIN);        // 4 MB
    float*       scale = (float*)(ws + (size_t)NTOK * DIN + WELEMS);     // 64 KB
    char*        tail  = ws + (size_t)NTOK * DIN + WELEMS + NTOK * 4;
    double*      wsum  = (double*)tail;                                  // 8 B
    double*      part  = (double*)(tail + 4096);                         // 4 KB

    wabs_partial<<<NPART, 256, 0, stream>>>(w, part);
    wtern<<<WELEMS / (256 * 4), 256, 0, stream>>>(w, part, wsum, t);
    ln_quant<<<NTOK / 4, 256, 0, stream>>>(x, wsum, q, scale);
    gemm_i8<<<(NTOK / 256) * (DOUT / 256), 512, 0, stream>>>(q, t, scale, bias, out);
}